// Round 3
// baseline (228.362 us; speedup 1.0000x reference)
//
#include <hip/hip_runtime.h>
#include <hip/hip_bf16.h>

typedef float f32x4 __attribute__((ext_vector_type(4)));
typedef short s16x8 __attribute__((ext_vector_type(8)));
typedef unsigned short u16;

__device__ __forceinline__ u16 f2bf(float f) {
    unsigned u = __float_as_uint(f);
    u += 0x7fffu + ((u >> 16) & 1u);   // RNE
    return (u16)(u >> 16);
}

// ---------------- weight transpose + bf16 cast: wt[c][k] = w[k][c] ----------------
__global__ __launch_bounds__(256) void transpose_w(
    const float* w0, const float* w1, const float* w2,
    const float* w3, const float* w4, const float* w5, u16* wt_base) {
    __shared__ float tile[64][65];
    int z = blockIdx.z;
    const float* src = z==0?w0 : z==1?w1 : z==2?w2 : z==3?w3 : z==4?w4 : w5;
    u16* dst = wt_base + (size_t)z * 262144;
    int r0 = blockIdx.y * 64, c0 = blockIdx.x * 64;
    int t = threadIdx.x;
    for (int it = 0; it < 4; ++it) {
        int idx = it * 256 + t;            // float4 chunk id, 0..1023
        int r = idx >> 4, c4 = (idx & 15) << 2;
        float4 v = *(const float4*)(src + (size_t)(r0 + r) * 512 + c0 + c4);
        tile[r][c4+0] = v.x; tile[r][c4+1] = v.y; tile[r][c4+2] = v.z; tile[r][c4+3] = v.w;
    }
    __syncthreads();
    for (int it = 0; it < 4; ++it) {
        int idx = it * 256 + t;
        int c = idx >> 4, r4 = (idx & 15) << 2;
        ushort4 o;
        o.x = f2bf(tile[r4+0][c]); o.y = f2bf(tile[r4+1][c]);
        o.z = f2bf(tile[r4+2][c]); o.w = f2bf(tile[r4+3][c]);
        *(ushort4*)(dst + (size_t)(c0 + c) * 512 + r0 + r4) = o;
    }
}

// ---------------- projections: [4096x512 f32] @ W -> bf16 [b,h,n,64] ----------------
// z=0: x*w_qk->qk, z=1: x*w_v->v, z=2: ctx*w_cqk->cqk, z=3: ctx*w_cv->cv
__global__ __launch_bounds__(256) void proj_kernel(
    const float* x, const float* ctx, const u16* wt, u16* proj_base) {
    __shared__ u16 Al[128][72];
    __shared__ u16 Bl[64][72];
    int z = blockIdx.z;
    const float* A = (z < 2) ? x : ctx;
    int p = (z==1) ? 2 : (z==2) ? 1 : z;          // buffer slot: qk,v,cqk,cv -> 0,2,1,3
    const u16* Wt = wt + (size_t)p * 262144;
    u16* dst = proj_base + (size_t)p * 2097152;
    int m0 = blockIdx.y * 128, n0 = blockIdx.x * 64;
    int t = threadIdx.x, w = t >> 6, l = t & 63, lg = l >> 4, lr = l & 15;
    f32x4 acc[2][4] = {};
    for (int k0 = 0; k0 < 512; k0 += 64) {
        __syncthreads();
        for (int it = 0; it < 8; ++it) {           // A: 128x64 f32 -> bf16
            int idx = it * 256 + t;
            int r = idx >> 4, c4 = (idx & 15) << 2;
            float4 v = *(const float4*)(A + (size_t)(m0 + r) * 512 + k0 + c4);
            ushort4 o = { f2bf(v.x), f2bf(v.y), f2bf(v.z), f2bf(v.w) };
            *(ushort4*)&Al[r][c4] = o;
        }
        for (int it = 0; it < 2; ++it) {           // Wt: 64x64 bf16
            int idx = it * 256 + t;
            int r = idx >> 3, c8 = (idx & 7) << 3;
            *(s16x8*)&Bl[r][c8] = *(const s16x8*)(Wt + (size_t)(n0 + r) * 512 + k0 + c8);
        }
        __syncthreads();
        for (int ks = 0; ks < 2; ++ks) {
            s16x8 a[2], b[4];
            for (int mi = 0; mi < 2; ++mi) a[mi] = *(const s16x8*)&Al[w*32 + mi*16 + lr][ks*32 + lg*8];
            for (int nf = 0; nf < 4; ++nf) b[nf] = *(const s16x8*)&Bl[nf*16 + lr][ks*32 + lg*8];
            for (int mi = 0; mi < 2; ++mi)
                for (int nf = 0; nf < 4; ++nf)
                    acc[mi][nf] = __builtin_amdgcn_mfma_f32_16x16x32_bf16(a[mi], b[nf], acc[mi][nf], 0, 0, 0);
        }
    }
    for (int mi = 0; mi < 2; ++mi) {
        int row = m0 + w*32 + mi*16 + lg*4;
        for (int nf = 0; nf < 4; ++nf) {
            int c = n0 + nf*16 + lr;
            int h = c >> 6, d = c & 63;
            for (int r = 0; r < 4; ++r) {
                int rr = row + r;
                int b = rr >> 11, n = rr & 2047;
                dst[(((size_t)b*8 + h)*2048 + n)*64 + d] = f2bf(acc[mi][nf][r]);
            }
        }
    }
}

// ---------------- bidirectional attention (one direction per launch) ----------------
// Arows: softmax-dim-owner rows [b,h,2048,64]; Brows: other side; Vals: values.
// Out[b][row][h*64+d] = sum_j exp(S)*Vals[j] / sum_j exp(S),  S = Arows . Brows^T / 8
__global__ __launch_bounds__(256) void attn_kernel(
    const u16* Arows, const u16* Brows, const u16* Vals, u16* Out) {
    __shared__ u16 Bl[128][72];     // B-rows tile (K-contig)
    __shared__ u16 Vt[64][136];     // values transposed [d][j]
    __shared__ u16 Pl[64][136];     // P, per-wave-private 16-row bands
    int bh = blockIdx.y;
    int b = bh >> 3, h = bh & 7;
    int i0 = blockIdx.x * 64;
    int t = threadIdx.x, w = t >> 6, l = t & 63, lg = l >> 4, lr = l & 15;
    const size_t base = (size_t)bh * 2048 * 64;
    s16x8 aq[2];
    for (int ks = 0; ks < 2; ++ks)
        aq[ks] = *(const s16x8*)(Arows + base + (size_t)(i0 + w*16 + lr) * 64 + ks*32 + lg*8);
    f32x4 acc_o[4] = {};
    float den[4] = {0.f, 0.f, 0.f, 0.f};
    const float scale = 0.125f;
    for (int j0 = 0; j0 < 2048; j0 += 128) {
        __syncthreads();
        for (int it = 0; it < 4; ++it) {           // stage B rows 128x64
            int idx = it * 256 + t;
            int r = idx >> 3, c8 = (idx & 7) << 3;
            *(s16x8*)&Bl[r][c8] = *(const s16x8*)(Brows + base + (size_t)(j0 + r) * 64 + c8);
        }
        for (int it = 0; it < 8; ++it) {           // stage V transposed
            int idx = it * 256 + t;
            int r = idx & 127, d4 = (idx >> 7) << 2;
            ushort4 v = *(const ushort4*)(Vals + base + (size_t)(j0 + r) * 64 + d4);
            Vt[d4+0][r] = v.x; Vt[d4+1][r] = v.y; Vt[d4+2][r] = v.z; Vt[d4+3][r] = v.w;
        }
        __syncthreads();
        f32x4 s[8];
        for (int nf = 0; nf < 8; ++nf) s[nf] = (f32x4){0.f,0.f,0.f,0.f};
        for (int nf = 0; nf < 8; ++nf)
            for (int ks = 0; ks < 2; ++ks) {
                s16x8 bf = *(const s16x8*)&Bl[nf*16 + lr][ks*32 + lg*8];
                s[nf] = __builtin_amdgcn_mfma_f32_16x16x32_bf16(aq[ks], bf, s[nf], 0, 0, 0);
            }
        float pd[4] = {0.f, 0.f, 0.f, 0.f};
        for (int nf = 0; nf < 8; ++nf)
            for (int r = 0; r < 4; ++r) {
                float pv = __expf(s[nf][r] * scale);
                pd[r] += pv;
                Pl[w*16 + lg*4 + r][nf*16 + lr] = f2bf(pv);
            }
        for (int m = 1; m < 16; m <<= 1)
            for (int r = 0; r < 4; ++r) pd[r] += __shfl_xor(pd[r], m);
        for (int r = 0; r < 4; ++r) den[r] += pd[r];
        for (int ks2 = 0; ks2 < 4; ++ks2) {        // PV: out += P @ V
            s16x8 ap = *(const s16x8*)&Pl[w*16 + lr][ks2*32 + lg*8];
            for (int nf = 0; nf < 4; ++nf) {
                s16x8 bv = *(const s16x8*)&Vt[nf*16 + lr][ks2*32 + lg*8];
                acc_o[nf] = __builtin_amdgcn_mfma_f32_16x16x32_bf16(ap, bv, acc_o[nf], 0, 0, 0);
            }
        }
    }
    for (int nf = 0; nf < 4; ++nf)
        for (int r = 0; r < 4; ++r) {
            int row = i0 + w*16 + lg*4 + r;
            int c = h*64 + nf*16 + lr;
            Out[((size_t)b*2048 + row)*512 + c] = f2bf(acc_o[nf][r] / den[r]);
        }
}

// ---------------- output GEMM: merged bf16 [4096x512] @ W + bias -> d_out FLOAT32 ----------------
__global__ __launch_bounds__(256) void out_gemm(
    const u16* heads_base, const u16* wt, const float* bias0, const float* bias1, float* out) {
    __shared__ u16 Al[128][72];
    __shared__ u16 Bl[64][72];
    int z = blockIdx.z;
    const u16* A = heads_base + (size_t)z * 2097152;
    const u16* Wt = wt + (size_t)(4 + z) * 262144;
    const float* bias = z ? bias1 : bias0;
    float* dst = out + (size_t)z * 2097152;        // f32 elements per output
    int m0 = blockIdx.y * 128, n0 = blockIdx.x * 64;
    int t = threadIdx.x, w = t >> 6, l = t & 63, lg = l >> 4, lr = l & 15;
    f32x4 acc[2][4] = {};
    for (int k0 = 0; k0 < 512; k0 += 64) {
        __syncthreads();
        for (int it = 0; it < 4; ++it) {
            int idx = it * 256 + t;
            int r = idx >> 3, c8 = (idx & 7) << 3;
            *(s16x8*)&Al[r][c8] = *(const s16x8*)(A + (size_t)(m0 + r) * 512 + k0 + c8);
        }
        for (int it = 0; it < 2; ++it) {
            int idx = it * 256 + t;
            int r = idx >> 3, c8 = (idx & 7) << 3;
            *(s16x8*)&Bl[r][c8] = *(const s16x8*)(Wt + (size_t)(n0 + r) * 512 + k0 + c8);
        }
        __syncthreads();
        for (int ks = 0; ks < 2; ++ks) {
            s16x8 a[2], b[4];
            for (int mi = 0; mi < 2; ++mi) a[mi] = *(const s16x8*)&Al[w*32 + mi*16 + lr][ks*32 + lg*8];
            for (int nf = 0; nf < 4; ++nf) b[nf] = *(const s16x8*)&Bl[nf*16 + lr][ks*32 + lg*8];
            for (int mi = 0; mi < 2; ++mi)
                for (int nf = 0; nf < 4; ++nf)
                    acc[mi][nf] = __builtin_amdgcn_mfma_f32_16x16x32_bf16(a[mi], b[nf], acc[mi][nf], 0, 0, 0);
        }
    }
    for (int mi = 0; mi < 2; ++mi) {
        int row = m0 + w*32 + mi*16 + lg*4;
        for (int nf = 0; nf < 4; ++nf) {
            int c = n0 + nf*16 + lr;
            float bv = bias[c];
            for (int r = 0; r < 4; ++r)
                dst[(size_t)(row + r) * 512 + c] = acc[mi][nf][r] + bv;   // f32 store
        }
    }
}

extern "C" void kernel_launch(void* const* d_in, const int* in_sizes, int n_in,
                              void* d_out, int out_size, void* d_ws, size_t ws_size,
                              hipStream_t stream) {
    const float* x      = (const float*)d_in[0];
    const float* ctx    = (const float*)d_in[1];
    const float* w_qk   = (const float*)d_in[2];
    const float* w_cqk  = (const float*)d_in[3];
    const float* w_v    = (const float*)d_in[4];
    const float* w_cv   = (const float*)d_in[5];
    const float* w_out  = (const float*)d_in[6];
    const float* b_out  = (const float*)d_in[7];
    const float* w_cout = (const float*)d_in[8];
    const float* b_cout = (const float*)d_in[9];

    u16* ws   = (u16*)d_ws;
    u16* wt   = ws;                       // 6 * 262144 bf16 (w_qk,w_cqk,w_v,w_cv,w_out,w_cout transposed)
    u16* proj = ws + 1572864;             // qk, cqk, v, cv : 4 * 2097152, layout [b,h,n,64]
    u16* qk   = proj;
    u16* cqk  = proj + 2097152;
    u16* v    = proj + 2 * 2097152;
    u16* cv   = proj + 3 * 2097152;
    u16* outh = proj + 4 * 2097152;       // merged [b,n,512]
    u16* ctxh = proj + 5 * 2097152;
    float* out = (float*)d_out;           // reference output dtype is FLOAT32

    hipLaunchKernelGGL(transpose_w, dim3(8, 8, 6), dim3(256), 0, stream,
                       w_qk, w_cqk, w_v, w_cv, w_out, w_cout, wt);
    hipLaunchKernelGGL(proj_kernel, dim3(8, 32, 4), dim3(256), 0, stream, x, ctx, wt, proj);
    hipLaunchKernelGGL(attn_kernel, dim3(32, 16), dim3(256), 0, stream, qk, cqk, cv, outh);
    hipLaunchKernelGGL(attn_kernel, dim3(32, 16), dim3(256), 0, stream, cqk, qk, v, ctxh);
    hipLaunchKernelGGL(out_gemm, dim3(8, 32, 2), dim3(256), 0, stream, outh, wt, b_out, b_cout, out);
}

// Round 4
// 153.477 us; speedup vs baseline: 1.4879x; 1.4879x over previous
//
#include <hip/hip_runtime.h>
#include <hip/hip_bf16.h>

typedef float f32x4 __attribute__((ext_vector_type(4)));
typedef short s16x8 __attribute__((ext_vector_type(8)));
typedef unsigned short u16;

__device__ __forceinline__ u16 f2bf(float f) {
    unsigned u = __float_as_uint(f);
    u += 0x7fffu + ((u >> 16) & 1u);   // RNE
    return (u16)(u >> 16);
}

// ---------------- weight transpose + bf16 cast: wt[c][k] = w[k][c] ----------------
__global__ __launch_bounds__(256) void transpose_w(
    const float* w0, const float* w1, const float* w2,
    const float* w3, const float* w4, const float* w5, u16* wt_base) {
    __shared__ float tile[64][65];
    int z = blockIdx.z;
    const float* src = z==0?w0 : z==1?w1 : z==2?w2 : z==3?w3 : z==4?w4 : w5;
    u16* dst = wt_base + (size_t)z * 262144;
    int r0 = blockIdx.y * 64, c0 = blockIdx.x * 64;
    int t = threadIdx.x;
    for (int it = 0; it < 4; ++it) {
        int idx = it * 256 + t;            // float4 chunk id, 0..1023
        int r = idx >> 4, c4 = (idx & 15) << 2;
        float4 v = *(const float4*)(src + (size_t)(r0 + r) * 512 + c0 + c4);
        tile[r][c4+0] = v.x; tile[r][c4+1] = v.y; tile[r][c4+2] = v.z; tile[r][c4+3] = v.w;
    }
    __syncthreads();
    for (int it = 0; it < 4; ++it) {
        int idx = it * 256 + t;
        int c = idx >> 4, r4 = (idx & 15) << 2;
        ushort4 o;
        o.x = f2bf(tile[r4+0][c]); o.y = f2bf(tile[r4+1][c]);
        o.z = f2bf(tile[r4+2][c]); o.w = f2bf(tile[r4+3][c]);
        *(ushort4*)(dst + (size_t)(c0 + c) * 512 + r0 + r4) = o;
    }
}

// ---------------- projections: [4096x512 f32] @ W -> bf16 ----------------
// z=0: x*w_qk -> qk [b,h,n,64]        (slot 0)
// z=1: x*w_v  -> vt [b,h,64,2048] TR  (slot 2)
// z=2: ctx*w_cqk -> cqk [b,h,n,64]    (slot 1)
// z=3: ctx*w_cv  -> cvt [b,h,64,2048] TR (slot 3)
__global__ __launch_bounds__(256) void proj_kernel(
    const float* x, const float* ctx, const u16* wt, u16* proj_base) {
    __shared__ u16 Al[128][72];
    __shared__ u16 Bl[64][72];
    int z = blockIdx.z;
    const float* A = (z < 2) ? x : ctx;
    int p = (z==1) ? 2 : (z==2) ? 1 : z;          // buffer slot
    const u16* Wt = wt + (size_t)p * 262144;
    u16* dst = proj_base + (size_t)p * 2097152;
    int m0 = blockIdx.y * 128, n0 = blockIdx.x * 64;
    int t = threadIdx.x, w = t >> 6, l = t & 63, lg = l >> 4, lr = l & 15;
    f32x4 acc[2][4] = {};
    for (int k0 = 0; k0 < 512; k0 += 64) {
        __syncthreads();
        for (int it = 0; it < 8; ++it) {           // A: 128x64 f32 -> bf16
            int idx = it * 256 + t;
            int r = idx >> 4, c4 = (idx & 15) << 2;
            float4 v = *(const float4*)(A + (size_t)(m0 + r) * 512 + k0 + c4);
            ushort4 o = { f2bf(v.x), f2bf(v.y), f2bf(v.z), f2bf(v.w) };
            *(ushort4*)&Al[r][c4] = o;
        }
        for (int it = 0; it < 2; ++it) {           // Wt: 64x64 bf16
            int idx = it * 256 + t;
            int r = idx >> 3, c8 = (idx & 7) << 3;
            *(s16x8*)&Bl[r][c8] = *(const s16x8*)(Wt + (size_t)(n0 + r) * 512 + k0 + c8);
        }
        __syncthreads();
        for (int ks = 0; ks < 2; ++ks) {
            s16x8 a[2], b[4];
            for (int mi = 0; mi < 2; ++mi) a[mi] = *(const s16x8*)&Al[w*32 + mi*16 + lr][ks*32 + lg*8];
            for (int nf = 0; nf < 4; ++nf) b[nf] = *(const s16x8*)&Bl[nf*16 + lr][ks*32 + lg*8];
            for (int mi = 0; mi < 2; ++mi)
                for (int nf = 0; nf < 4; ++nf)
                    acc[mi][nf] = __builtin_amdgcn_mfma_f32_16x16x32_bf16(a[mi], b[nf], acc[mi][nf], 0, 0, 0);
        }
    }
    if (z & 1) {
        // transposed output [b,h,d,2048]: thread packs 4 consecutive n (rows) for fixed d
        for (int mi = 0; mi < 2; ++mi) {
            int row = m0 + w*32 + mi*16 + lg*4;
            int b = row >> 11, n = row & 2047;
            for (int nf = 0; nf < 4; ++nf) {
                int c = n0 + nf*16 + lr;
                int h = c >> 6, d = c & 63;
                ushort4 o = { f2bf(acc[mi][nf][0]), f2bf(acc[mi][nf][1]),
                              f2bf(acc[mi][nf][2]), f2bf(acc[mi][nf][3]) };
                *(ushort4*)(dst + (((size_t)b*8 + h)*64 + d)*2048 + n) = o;
            }
        }
    } else {
        for (int mi = 0; mi < 2; ++mi) {
            int row = m0 + w*32 + mi*16 + lg*4;
            for (int nf = 0; nf < 4; ++nf) {
                int c = n0 + nf*16 + lr;
                int h = c >> 6, d = c & 63;
                for (int r = 0; r < 4; ++r) {
                    int rr = row + r;
                    int b = rr >> 11, n = rr & 2047;
                    dst[(((size_t)b*8 + h)*2048 + n)*64 + d] = f2bf(acc[mi][nf][r]);
                }
            }
        }
    }
}

// ---------------- fused bidirectional attention ----------------
// dir 0: A=qk, B=cqk, VT=cvt, Out=outh ; dir 1: A=cqk, B=qk, VT=vt, Out=ctxh
// Out[b][row][h*64+d] = sum_j exp(S/8)*V[j][d] / sum_j exp(S/8),  S = A . B^T
__global__ __launch_bounds__(256, 4) void attn_kernel(
    const u16* qk, const u16* cqk, const u16* vtg, const u16* cvtg,
    u16* outh, u16* ctxh) {
    __shared__ u16 BP[128 * 72];    // B-tile [128][72]; reused as P [64][136]
    __shared__ u16 Vt[64 * 136];    // V^T tile [d][j]
    int dir = blockIdx.z;
    const u16* Arows = dir ? cqk : qk;
    const u16* Brows = dir ? qk  : cqk;
    const u16* VTg   = dir ? vtg : cvtg;
    u16* Out         = dir ? ctxh : outh;
    int bh = blockIdx.y;
    int b = bh >> 3, h = bh & 7;
    int i0 = blockIdx.x * 64;
    int t = threadIdx.x, w = t >> 6, l = t & 63, lg = l >> 4, lr = l & 15;
    const size_t base  = (size_t)bh * 2048 * 64;   // qk/cqk [bh][2048][64]
    const size_t vbase = (size_t)bh * 64 * 2048;   // vt/cvt [bh][64][2048]
    s16x8 aq[2];
    for (int ks = 0; ks < 2; ++ks)
        aq[ks] = *(const s16x8*)(Arows + base + (size_t)(i0 + w*16 + lr) * 64 + ks*32 + lg*8);
    f32x4 acc_o[4] = {};
    float den[4] = {0.f, 0.f, 0.f, 0.f};
    const float SC2 = 0.125f * 1.44269504088896f;  // /sqrt(64) * log2(e)
    for (int j0 = 0; j0 < 2048; j0 += 128) {
        __syncthreads();                            // (A) prev PV reads done
        for (int it = 0; it < 4; ++it) {            // stage B rows 128x64 (vector)
            int c = it * 256 + t;
            int r = c >> 3, c8 = c & 7;
            *(s16x8*)&BP[r*72 + c8*8] = *(const s16x8*)(Brows + base + (size_t)(j0 + r) * 64 + c8*8);
        }
        for (int it = 0; it < 4; ++it) {            // stage V^T 64x128 (vector, from transposed global)
            int c = it * 256 + t;
            int d = c >> 4, c16 = c & 15;
            *(s16x8*)&Vt[d*136 + c16*8] = *(const s16x8*)(VTg + vbase + (size_t)d*2048 + j0 + c16*8);
        }
        __syncthreads();                            // (B) staging visible
        f32x4 s[8];
        for (int nf = 0; nf < 8; ++nf) s[nf] = (f32x4){0.f,0.f,0.f,0.f};
        for (int nf = 0; nf < 8; ++nf)
            for (int ks = 0; ks < 2; ++ks) {
                s16x8 bf = *(const s16x8*)&BP[(nf*16 + lr)*72 + ks*32 + lg*8];
                s[nf] = __builtin_amdgcn_mfma_f32_16x16x32_bf16(aq[ks], bf, s[nf], 0, 0, 0);
            }
        __syncthreads();                            // (C) all QK reads of BP done -> reuse as P
        float pd[4] = {0.f, 0.f, 0.f, 0.f};
        for (int nf = 0; nf < 8; ++nf)
            for (int r = 0; r < 4; ++r) {
                float pv = exp2f(s[nf][r] * SC2);
                pd[r] += pv;
                BP[(w*16 + lg*4 + r)*136 + nf*16 + lr] = f2bf(pv);
            }
        for (int m = 1; m < 16; m <<= 1)
            for (int r = 0; r < 4; ++r) pd[r] += __shfl_xor(pd[r], m);
        for (int r = 0; r < 4; ++r) den[r] += pd[r];
        for (int ks2 = 0; ks2 < 4; ++ks2) {         // PV: out += P @ V  (wave-private P band)
            s16x8 ap = *(const s16x8*)&BP[(w*16 + lr)*136 + ks2*32 + lg*8];
            for (int nf = 0; nf < 4; ++nf) {
                s16x8 bv = *(const s16x8*)&Vt[(nf*16 + lr)*136 + ks2*32 + lg*8];
                acc_o[nf] = __builtin_amdgcn_mfma_f32_16x16x32_bf16(ap, bv, acc_o[nf], 0, 0, 0);
            }
        }
    }
    for (int nf = 0; nf < 4; ++nf)
        for (int r = 0; r < 4; ++r) {
            int row = i0 + w*16 + lg*4 + r;
            int c = h*64 + nf*16 + lr;
            Out[((size_t)b*2048 + row)*512 + c] = f2bf(acc_o[nf][r] / den[r]);
        }
}

// ---------------- output GEMM: merged bf16 [4096x512] @ W + bias -> d_out FLOAT32 ----------------
__global__ __launch_bounds__(256) void out_gemm(
    const u16* heads_base, const u16* wt, const float* bias0, const float* bias1, float* out) {
    __shared__ u16 Al[128][72];
    __shared__ u16 Bl[64][72];
    int z = blockIdx.z;
    const u16* A = heads_base + (size_t)z * 2097152;
    const u16* Wt = wt + (size_t)(4 + z) * 262144;
    const float* bias = z ? bias1 : bias0;
    float* dst = out + (size_t)z * 2097152;
    int m0 = blockIdx.y * 128, n0 = blockIdx.x * 64;
    int t = threadIdx.x, w = t >> 6, l = t & 63, lg = l >> 4, lr = l & 15;
    f32x4 acc[2][4] = {};
    for (int k0 = 0; k0 < 512; k0 += 64) {
        __syncthreads();
        for (int it = 0; it < 4; ++it) {
            int idx = it * 256 + t;
            int r = idx >> 3, c8 = (idx & 7) << 3;
            *(s16x8*)&Al[r][c8] = *(const s16x8*)(A + (size_t)(m0 + r) * 512 + k0 + c8);
        }
        for (int it = 0; it < 2; ++it) {
            int idx = it * 256 + t;
            int r = idx >> 3, c8 = (idx & 7) << 3;
            *(s16x8*)&Bl[r][c8] = *(const s16x8*)(Wt + (size_t)(n0 + r) * 512 + k0 + c8);
        }
        __syncthreads();
        for (int ks = 0; ks < 2; ++ks) {
            s16x8 a[2], b[4];
            for (int mi = 0; mi < 2; ++mi) a[mi] = *(const s16x8*)&Al[w*32 + mi*16 + lr][ks*32 + lg*8];
            for (int nf = 0; nf < 4; ++nf) b[nf] = *(const s16x8*)&Bl[nf*16 + lr][ks*32 + lg*8];
            for (int mi = 0; mi < 2; ++mi)
                for (int nf = 0; nf < 4; ++nf)
                    acc[mi][nf] = __builtin_amdgcn_mfma_f32_16x16x32_bf16(a[mi], b[nf], acc[mi][nf], 0, 0, 0);
        }
    }
    for (int mi = 0; mi < 2; ++mi) {
        int row = m0 + w*32 + mi*16 + lg*4;
        for (int nf = 0; nf < 4; ++nf) {
            int c = n0 + nf*16 + lr;
            float bv = bias[c];
            for (int r = 0; r < 4; ++r)
                dst[(size_t)(row + r) * 512 + c] = acc[mi][nf][r] + bv;
        }
    }
}

extern "C" void kernel_launch(void* const* d_in, const int* in_sizes, int n_in,
                              void* d_out, int out_size, void* d_ws, size_t ws_size,
                              hipStream_t stream) {
    const float* x      = (const float*)d_in[0];
    const float* ctx    = (const float*)d_in[1];
    const float* w_qk   = (const float*)d_in[2];
    const float* w_cqk  = (const float*)d_in[3];
    const float* w_v    = (const float*)d_in[4];
    const float* w_cv   = (const float*)d_in[5];
    const float* w_out  = (const float*)d_in[6];
    const float* b_out  = (const float*)d_in[7];
    const float* w_cout = (const float*)d_in[8];
    const float* b_cout = (const float*)d_in[9];

    u16* ws   = (u16*)d_ws;
    u16* wt   = ws;                       // 6 * 262144 bf16 weights^T
    u16* proj = ws + 1572864;             // slot0 qk [bh,2048,64], slot1 cqk, slot2 vt [bh,64,2048], slot3 cvt
    u16* qk   = proj;
    u16* cqk  = proj + 2097152;
    u16* vt   = proj + 2 * 2097152;
    u16* cvt  = proj + 3 * 2097152;
    u16* outh = proj + 4 * 2097152;       // merged [b,n,512]
    u16* ctxh = proj + 5 * 2097152;
    float* out = (float*)d_out;           // f32 outputs

    hipLaunchKernelGGL(transpose_w, dim3(8, 8, 6), dim3(256), 0, stream,
                       w_qk, w_cqk, w_v, w_cv, w_out, w_cout, wt);
    hipLaunchKernelGGL(proj_kernel, dim3(8, 32, 4), dim3(256), 0, stream, x, ctx, wt, proj);
    hipLaunchKernelGGL(attn_kernel, dim3(32, 16, 2), dim3(256), 0, stream, qk, cqk, vt, cvt, outh, ctxh);
    hipLaunchKernelGGL(out_gemm, dim3(8, 32, 2), dim3(256), 0, stream, outh, wt, b_out, b_cout, out);
}

// Round 5
// 138.009 us; speedup vs baseline: 1.6547x; 1.1121x over previous
//
#include <hip/hip_runtime.h>
#include <hip/hip_bf16.h>

typedef float f32x4 __attribute__((ext_vector_type(4)));
typedef short s16x8 __attribute__((ext_vector_type(8)));
typedef unsigned short u16;

__device__ __forceinline__ u16 f2bf(float f) {
    unsigned u = __float_as_uint(f);
    u += 0x7fffu + ((u >> 16) & 1u);   // RNE
    return (u16)(u >> 16);
}

// ---------------- weight transpose + bf16 cast: wt[c][k] = w[k][c] ----------------
__global__ __launch_bounds__(256) void transpose_w(
    const float* w0, const float* w1, const float* w2,
    const float* w3, const float* w4, const float* w5, u16* wt_base) {
    __shared__ float tile[64][65];
    int z = blockIdx.z;
    const float* src = z==0?w0 : z==1?w1 : z==2?w2 : z==3?w3 : z==4?w4 : w5;
    u16* dst = wt_base + (size_t)z * 262144;
    int r0 = blockIdx.y * 64, c0 = blockIdx.x * 64;
    int t = threadIdx.x;
    for (int it = 0; it < 4; ++it) {
        int idx = it * 256 + t;            // float4 chunk id, 0..1023
        int r = idx >> 4, c4 = (idx & 15) << 2;
        float4 v = *(const float4*)(src + (size_t)(r0 + r) * 512 + c0 + c4);
        tile[r][c4+0] = v.x; tile[r][c4+1] = v.y; tile[r][c4+2] = v.z; tile[r][c4+3] = v.w;
    }
    __syncthreads();
    for (int it = 0; it < 4; ++it) {
        int idx = it * 256 + t;
        int c = idx >> 4, r4 = (idx & 15) << 2;
        ushort4 o;
        o.x = f2bf(tile[r4+0][c]); o.y = f2bf(tile[r4+1][c]);
        o.z = f2bf(tile[r4+2][c]); o.w = f2bf(tile[r4+3][c]);
        *(ushort4*)(dst + (size_t)(c0 + c) * 512 + r0 + r4) = o;
    }
}

// ---------------- projections: [4096x512 f32] @ W -> bf16 ----------------
// z=0: x*w_qk -> qk [b,h,n,64]        (slot 0)
// z=1: x*w_v  -> vt [b,h,64,2048] TR  (slot 2)
// z=2: ctx*w_cqk -> cqk [b,h,n,64]    (slot 1)
// z=3: ctx*w_cv  -> cvt [b,h,64,2048] TR (slot 3)
__global__ __launch_bounds__(256) void proj_kernel(
    const float* x, const float* ctx, const u16* wt, u16* proj_base) {
    __shared__ u16 Al[128][72];
    __shared__ u16 Bl[64][72];
    int z = blockIdx.z;
    const float* A = (z < 2) ? x : ctx;
    int p = (z==1) ? 2 : (z==2) ? 1 : z;          // buffer slot
    const u16* Wt = wt + (size_t)p * 262144;
    u16* dst = proj_base + (size_t)p * 2097152;
    int m0 = blockIdx.y * 128, n0 = blockIdx.x * 64;
    int t = threadIdx.x, w = t >> 6, l = t & 63, lg = l >> 4, lr = l & 15;
    f32x4 acc[2][4] = {};
    for (int k0 = 0; k0 < 512; k0 += 64) {
        __syncthreads();
        for (int it = 0; it < 8; ++it) {           // A: 128x64 f32 -> bf16
            int idx = it * 256 + t;
            int r = idx >> 4, c4 = (idx & 15) << 2;
            float4 v = *(const float4*)(A + (size_t)(m0 + r) * 512 + k0 + c4);
            ushort4 o = { f2bf(v.x), f2bf(v.y), f2bf(v.z), f2bf(v.w) };
            *(ushort4*)&Al[r][c4] = o;
        }
        for (int it = 0; it < 2; ++it) {           // Wt: 64x64 bf16
            int idx = it * 256 + t;
            int r = idx >> 3, c8 = (idx & 7) << 3;
            *(s16x8*)&Bl[r][c8] = *(const s16x8*)(Wt + (size_t)(n0 + r) * 512 + k0 + c8);
        }
        __syncthreads();
        for (int ks = 0; ks < 2; ++ks) {
            s16x8 a[2], b[4];
            for (int mi = 0; mi < 2; ++mi) a[mi] = *(const s16x8*)&Al[w*32 + mi*16 + lr][ks*32 + lg*8];
            for (int nf = 0; nf < 4; ++nf) b[nf] = *(const s16x8*)&Bl[nf*16 + lr][ks*32 + lg*8];
            for (int mi = 0; mi < 2; ++mi)
                for (int nf = 0; nf < 4; ++nf)
                    acc[mi][nf] = __builtin_amdgcn_mfma_f32_16x16x32_bf16(a[mi], b[nf], acc[mi][nf], 0, 0, 0);
        }
    }
    if (z & 1) {
        // transposed output [b,h,d,2048]: thread packs 4 consecutive n (rows) for fixed d
        for (int mi = 0; mi < 2; ++mi) {
            int row = m0 + w*32 + mi*16 + lg*4;
            int b = row >> 11, n = row & 2047;
            for (int nf = 0; nf < 4; ++nf) {
                int c = n0 + nf*16 + lr;
                int h = c >> 6, d = c & 63;
                ushort4 o = { f2bf(acc[mi][nf][0]), f2bf(acc[mi][nf][1]),
                              f2bf(acc[mi][nf][2]), f2bf(acc[mi][nf][3]) };
                *(ushort4*)(dst + (((size_t)b*8 + h)*64 + d)*2048 + n) = o;
            }
        }
    } else {
        for (int mi = 0; mi < 2; ++mi) {
            int row = m0 + w*32 + mi*16 + lg*4;
            for (int nf = 0; nf < 4; ++nf) {
                int c = n0 + nf*16 + lr;
                int h = c >> 6, d = c & 63;
                for (int r = 0; r < 4; ++r) {
                    int rr = row + r;
                    int b = rr >> 11, n = rr & 2047;
                    dst[(((size_t)b*8 + h)*2048 + n)*64 + d] = f2bf(acc[mi][nf][r]);
                }
            }
        }
    }
}

// ---------------- fused bidirectional attention (swapped-QK in-register softmax) ----------------
// dir 0: A=qk, B=cqk, VT=cvt, Out=outh ; dir 1: A=cqk, B=qk, VT=vt, Out=ctxh
// All LDS tiles 16B-chunk XOR-swizzled by (row&7) for conflict-free b128 access.
__global__ __launch_bounds__(256, 4) void attn_kernel(
    const u16* qk, const u16* cqk, const u16* vtg, const u16* cvtg,
    u16* outh, u16* ctxh) {
    __shared__ u16 Bt[64 * 64];      // K-rows tile [j][k]
    __shared__ u16 Vs[64 * 64];      // V^T tile [d][j]
    __shared__ u16 Pt[4][16 * 64];   // per-wave P [i][j]
    int dir = blockIdx.z;
    const u16* Arows = dir ? cqk : qk;
    const u16* Brows = dir ? qk  : cqk;
    const u16* VTg   = dir ? vtg : cvtg;
    u16* Out         = dir ? ctxh : outh;
    int bh = blockIdx.y;
    int b = bh >> 3, h = bh & 7;
    int i0 = blockIdx.x * 64;
    int t = threadIdx.x, w = t >> 6, l = t & 63, lg = l >> 4, lr = l & 15;
    int m7 = lr & 7;
    const size_t base  = (size_t)bh * 2048 * 64;   // qk/cqk [bh][2048][64]
    const size_t vbase = (size_t)bh * 64 * 2048;   // vt/cvt [bh][64][2048]
    s16x8 aq[2];
    for (int ks = 0; ks < 2; ++ks)
        aq[ks] = *(const s16x8*)(Arows + base + (size_t)(i0 + w*16 + lr) * 64 + ks*32 + lg*8);
    f32x4 acc_o[4] = {};
    float den = 0.f;                                // partial, rows i=lr, this lane's j's
    const float SC2 = 0.125f * 1.44269504088896f;   // /sqrt(64) * log2(e)
    u16* pw = &Pt[w][0];
    int sr = t >> 3, sc = t & 7;
    for (int j0 = 0; j0 < 2048; j0 += 64) {
        __syncthreads();                            // prev iter's LDS reads done
        for (int it = 0; it < 2; ++it) {            // stage Bt 64x64 + Vs 64x64, swizzled
            int r = it * 32 + sr;
            *(s16x8*)&Bt[r*64 + ((sc ^ (r & 7)) * 8)] =
                *(const s16x8*)(Brows + base + (size_t)(j0 + r) * 64 + sc * 8);
            *(s16x8*)&Vs[r*64 + ((sc ^ (r & 7)) * 8)] =
                *(const s16x8*)(VTg + vbase + (size_t)r * 2048 + j0 + sc * 8);
        }
        __syncthreads();                            // staging visible
        // swapped QK^T: s[nf][q] = S[i=lr][j = nf*16 + lg*4 + q]
        f32x4 s[4];
        for (int nf = 0; nf < 4; ++nf) {
            s[nf] = (f32x4){0.f, 0.f, 0.f, 0.f};
            for (int ks = 0; ks < 2; ++ks) {
                const s16x8 af = *(const s16x8*)&Bt[(nf*16 + lr)*64 + (((ks*4 + lg) ^ m7) * 8)];
                s[nf] = __builtin_amdgcn_mfma_f32_16x16x32_bf16(af, aq[ks], s[nf], 0, 0, 0);
            }
        }
        // exp, denominator partial, pack to bf16, store to wave-private P (swizzled)
        for (int nf = 0; nf < 4; ++nf) {
            float e0 = exp2f(s[nf][0] * SC2), e1 = exp2f(s[nf][1] * SC2);
            float e2 = exp2f(s[nf][2] * SC2), e3 = exp2f(s[nf][3] * SC2);
            den += (e0 + e1) + (e2 + e3);
            unsigned p0, p1;
            asm("v_cvt_pk_bf16_f32 %0, %1, %2" : "=v"(p0) : "v"(e0), "v"(e1));
            asm("v_cvt_pk_bf16_f32 %0, %1, %2" : "=v"(p1) : "v"(e2), "v"(e3));
            uint2 pp = { p0, p1 };
            // j = nf*16 + lg*4 + {0..3}: chunk = nf*2+(lg>>1), in-chunk off = (lg&1)*4
            *(uint2*)&pw[lr*64 + (((nf*2 + (lg >> 1)) ^ m7) * 8) + (lg & 1) * 4] = pp;
        }
        // PV: acc_o[nf] += P[i][k] * V^T[d][k]   (same-wave DS ordering makes P visible)
        for (int ks2 = 0; ks2 < 2; ++ks2) {
            const s16x8 ap = *(const s16x8*)&pw[lr*64 + (((ks2*4 + lg) ^ m7) * 8)];
            for (int nf = 0; nf < 4; ++nf) {
                const s16x8 bv = *(const s16x8*)&Vs[(nf*16 + lr)*64 + (((ks2*4 + lg) ^ m7) * 8)];
                acc_o[nf] = __builtin_amdgcn_mfma_f32_16x16x32_bf16(ap, bv, acc_o[nf], 0, 0, 0);
            }
        }
    }
    // finalize denominators: reduce across lg groups (rows i=lr), then fetch per output row
    den += __shfl_xor(den, 16);
    den += __shfl_xor(den, 32);
    float rq[4];
    for (int q = 0; q < 4; ++q) rq[q] = 1.0f / __shfl(den, lg*4 + q);
    for (int nf = 0; nf < 4; ++nf)
        for (int q = 0; q < 4; ++q) {
            int row = i0 + w*16 + lg*4 + q;
            int c = h*64 + nf*16 + lr;
            Out[((size_t)b*2048 + row)*512 + c] = f2bf(acc_o[nf][q] * rq[q]);
        }
}

// ---------------- output GEMM: merged bf16 [4096x512] @ W + bias -> d_out FLOAT32 ----------------
__global__ __launch_bounds__(256) void out_gemm(
    const u16* heads_base, const u16* wt, const float* bias0, const float* bias1, float* out) {
    __shared__ u16 Al[128][72];
    __shared__ u16 Bl[64][72];
    int z = blockIdx.z;
    const u16* A = heads_base + (size_t)z * 2097152;
    const u16* Wt = wt + (size_t)(4 + z) * 262144;
    const float* bias = z ? bias1 : bias0;
    float* dst = out + (size_t)z * 2097152;
    int m0 = blockIdx.y * 128, n0 = blockIdx.x * 64;
    int t = threadIdx.x, w = t >> 6, l = t & 63, lg = l >> 4, lr = l & 15;
    f32x4 acc[2][4] = {};
    for (int k0 = 0; k0 < 512; k0 += 64) {
        __syncthreads();
        for (int it = 0; it < 4; ++it) {
            int idx = it * 256 + t;
            int r = idx >> 3, c8 = (idx & 7) << 3;
            *(s16x8*)&Al[r][c8] = *(const s16x8*)(A + (size_t)(m0 + r) * 512 + k0 + c8);
        }
        for (int it = 0; it < 2; ++it) {
            int idx = it * 256 + t;
            int r = idx >> 3, c8 = (idx & 7) << 3;
            *(s16x8*)&Bl[r][c8] = *(const s16x8*)(Wt + (size_t)(n0 + r) * 512 + k0 + c8);
        }
        __syncthreads();
        for (int ks = 0; ks < 2; ++ks) {
            s16x8 a[2], b[4];
            for (int mi = 0; mi < 2; ++mi) a[mi] = *(const s16x8*)&Al[w*32 + mi*16 + lr][ks*32 + lg*8];
            for (int nf = 0; nf < 4; ++nf) b[nf] = *(const s16x8*)&Bl[nf*16 + lr][ks*32 + lg*8];
            for (int mi = 0; mi < 2; ++mi)
                for (int nf = 0; nf < 4; ++nf)
                    acc[mi][nf] = __builtin_amdgcn_mfma_f32_16x16x32_bf16(a[mi], b[nf], acc[mi][nf], 0, 0, 0);
        }
    }
    for (int mi = 0; mi < 2; ++mi) {
        int row = m0 + w*32 + mi*16 + lg*4;
        for (int nf = 0; nf < 4; ++nf) {
            int c = n0 + nf*16 + lr;
            float bv = bias[c];
            for (int r = 0; r < 4; ++r)
                dst[(size_t)(row + r) * 512 + c] = acc[mi][nf][r] + bv;
        }
    }
}

extern "C" void kernel_launch(void* const* d_in, const int* in_sizes, int n_in,
                              void* d_out, int out_size, void* d_ws, size_t ws_size,
                              hipStream_t stream) {
    const float* x      = (const float*)d_in[0];
    const float* ctx    = (const float*)d_in[1];
    const float* w_qk   = (const float*)d_in[2];
    const float* w_cqk  = (const float*)d_in[3];
    const float* w_v    = (const float*)d_in[4];
    const float* w_cv   = (const float*)d_in[5];
    const float* w_out  = (const float*)d_in[6];
    const float* b_out  = (const float*)d_in[7];
    const float* w_cout = (const float*)d_in[8];
    const float* b_cout = (const float*)d_in[9];

    u16* ws   = (u16*)d_ws;
    u16* wt   = ws;                       // 6 * 262144 bf16 weights^T
    u16* proj = ws + 1572864;             // slot0 qk [bh,2048,64], slot1 cqk, slot2 vt [bh,64,2048], slot3 cvt
    u16* qk   = proj;
    u16* cqk  = proj + 2097152;
    u16* vt   = proj + 2 * 2097152;
    u16* cvt  = proj + 3 * 2097152;
    u16* outh = proj + 4 * 2097152;       // merged [b,n,512]
    u16* ctxh = proj + 5 * 2097152;
    float* out = (float*)d_out;           // f32 outputs

    hipLaunchKernelGGL(transpose_w, dim3(8, 8, 6), dim3(256), 0, stream,
                       w_qk, w_cqk, w_v, w_cv, w_out, w_cout, wt);
    hipLaunchKernelGGL(proj_kernel, dim3(8, 32, 4), dim3(256), 0, stream, x, ctx, wt, proj);
    hipLaunchKernelGGL(attn_kernel, dim3(32, 16, 2), dim3(256), 0, stream, qk, cqk, vt, cvt, outh, ctxh);
    hipLaunchKernelGGL(out_gemm, dim3(8, 32, 2), dim3(256), 0, stream, outh, wt, b_out, b_cout, out);
}

// Round 6
// 126.005 us; speedup vs baseline: 1.8123x; 1.0953x over previous
//
#include <hip/hip_runtime.h>
#include <hip/hip_bf16.h>

typedef float f32x4 __attribute__((ext_vector_type(4)));
typedef short s16x8 __attribute__((ext_vector_type(8)));
typedef unsigned short u16;

__device__ __forceinline__ u16 f2bf(float f) {
    unsigned u = __float_as_uint(f);
    u += 0x7fffu + ((u >> 16) & 1u);   // RNE
    return (u16)(u >> 16);
}

#define GLDS16(gp, lp) __builtin_amdgcn_global_load_lds( \
    (const __attribute__((address_space(1))) void*)(gp), \
    (__attribute__((address_space(3))) void*)(lp), 16, 0, 0)

// ---------------- weight transpose + bf16 cast: wt[c][k] = w[k][c] ----------------
__global__ __launch_bounds__(256) void transpose_w(
    const float* w0, const float* w1, const float* w2,
    const float* w3, const float* w4, const float* w5, u16* wt_base) {
    __shared__ float tile[64][65];
    int z = blockIdx.z;
    const float* src = z==0?w0 : z==1?w1 : z==2?w2 : z==3?w3 : z==4?w4 : w5;
    u16* dst = wt_base + (size_t)z * 262144;
    int r0 = blockIdx.y * 64, c0 = blockIdx.x * 64;
    int t = threadIdx.x;
    for (int it = 0; it < 4; ++it) {
        int idx = it * 256 + t;
        int r = idx >> 4, c4 = (idx & 15) << 2;
        float4 v = *(const float4*)(src + (size_t)(r0 + r) * 512 + c0 + c4);
        tile[r][c4+0] = v.x; tile[r][c4+1] = v.y; tile[r][c4+2] = v.z; tile[r][c4+3] = v.w;
    }
    __syncthreads();
    for (int it = 0; it < 4; ++it) {
        int idx = it * 256 + t;
        int c = idx >> 4, r4 = (idx & 15) << 2;
        ushort4 o;
        o.x = f2bf(tile[r4+0][c]); o.y = f2bf(tile[r4+1][c]);
        o.z = f2bf(tile[r4+2][c]); o.w = f2bf(tile[r4+3][c]);
        *(ushort4*)(dst + (size_t)(c0 + c) * 512 + r0 + r4) = o;
    }
}

// ---------------- projections: [4096x512 f32] @ W -> bf16 ----------------
// z=0: x*w_qk -> qk [b,h,n,64]; z=1: x*w_v -> vt [b,h,64,2048] TR
// z=2: ctx*w_cqk -> cqk;        z=3: ctx*w_cv -> cvt TR
__global__ __launch_bounds__(256) void proj_kernel(
    const float* x, const float* ctx, const u16* wt, u16* proj_base) {
    __shared__ u16 Al[128][72];
    __shared__ u16 Bl[64][72];
    int z = blockIdx.z;
    const float* A = (z < 2) ? x : ctx;
    int p = (z==1) ? 2 : (z==2) ? 1 : z;
    const u16* Wt = wt + (size_t)p * 262144;
    u16* dst = proj_base + (size_t)p * 2097152;
    int m0 = blockIdx.y * 128, n0 = blockIdx.x * 64;
    int t = threadIdx.x, w = t >> 6, l = t & 63, lg = l >> 4, lr = l & 15;
    f32x4 acc[2][4] = {};
    for (int k0 = 0; k0 < 512; k0 += 64) {
        __syncthreads();
        for (int it = 0; it < 8; ++it) {
            int idx = it * 256 + t;
            int r = idx >> 4, c4 = (idx & 15) << 2;
            float4 v = *(const float4*)(A + (size_t)(m0 + r) * 512 + k0 + c4);
            ushort4 o = { f2bf(v.x), f2bf(v.y), f2bf(v.z), f2bf(v.w) };
            *(ushort4*)&Al[r][c4] = o;
        }
        for (int it = 0; it < 2; ++it) {
            int idx = it * 256 + t;
            int r = idx >> 3, c8 = (idx & 7) << 3;
            *(s16x8*)&Bl[r][c8] = *(const s16x8*)(Wt + (size_t)(n0 + r) * 512 + k0 + c8);
        }
        __syncthreads();
        for (int ks = 0; ks < 2; ++ks) {
            s16x8 a[2], b[4];
            for (int mi = 0; mi < 2; ++mi) a[mi] = *(const s16x8*)&Al[w*32 + mi*16 + lr][ks*32 + lg*8];
            for (int nf = 0; nf < 4; ++nf) b[nf] = *(const s16x8*)&Bl[nf*16 + lr][ks*32 + lg*8];
            for (int mi = 0; mi < 2; ++mi)
                for (int nf = 0; nf < 4; ++nf)
                    acc[mi][nf] = __builtin_amdgcn_mfma_f32_16x16x32_bf16(a[mi], b[nf], acc[mi][nf], 0, 0, 0);
        }
    }
    if (z & 1) {
        for (int mi = 0; mi < 2; ++mi) {
            int row = m0 + w*32 + mi*16 + lg*4;
            int b = row >> 11, n = row & 2047;
            for (int nf = 0; nf < 4; ++nf) {
                int c = n0 + nf*16 + lr;
                int h = c >> 6, d = c & 63;
                ushort4 o = { f2bf(acc[mi][nf][0]), f2bf(acc[mi][nf][1]),
                              f2bf(acc[mi][nf][2]), f2bf(acc[mi][nf][3]) };
                *(ushort4*)(dst + (((size_t)b*8 + h)*64 + d)*2048 + n) = o;
            }
        }
    } else {
        for (int mi = 0; mi < 2; ++mi) {
            int row = m0 + w*32 + mi*16 + lg*4;
            for (int nf = 0; nf < 4; ++nf) {
                int c = n0 + nf*16 + lr;
                int h = c >> 6, d = c & 63;
                for (int r = 0; r < 4; ++r) {
                    int rr = row + r;
                    int b = rr >> 11, n = rr & 2047;
                    dst[(((size_t)b*8 + h)*2048 + n)*64 + d] = f2bf(acc[mi][nf][r]);
                }
            }
        }
    }
}

// ---------------- fused bidirectional attention ----------------
// Block = 128 i-rows (4 waves x 32), j-tile 64, double-buffered DMA staging.
// Swapped QK^T in-register softmax; all LDS XOR-swizzled (16B chunk ^ (row&7)).
__global__ __launch_bounds__(256, 2) void attn_kernel(
    const u16* qk, const u16* cqk, const u16* vtg, const u16* cvtg,
    u16* outh, u16* ctxh) {
    __shared__ u16 Bt[2][64 * 64];   // K-rows tile [j][k]
    __shared__ u16 Vs[2][64 * 64];   // V^T tile [d][j]
    __shared__ u16 Pt[4][32 * 64];   // per-wave P [i local 32][j]
    // XCD-clustering swizzle (512 blocks, bijective): XCD k gets 4 (bh,dir) streams whole
    int id = blockIdx.x + 16 * (blockIdx.y + 16 * blockIdx.z);
    int v = ((id & 7) << 6) | (id >> 3);
    int dir = v >> 8;
    int bh  = (v >> 4) & 15;
    int i0  = (v & 15) * 128;
    const u16* Arows = dir ? cqk : qk;
    const u16* Brows = dir ? qk  : cqk;
    const u16* VTg   = dir ? vtg : cvtg;
    u16* Out         = dir ? ctxh : outh;
    int b = bh >> 3, h = bh & 7;
    int t = threadIdx.x, w = t >> 6, l = t & 63, lg = l >> 4, lr = l & 15, m7 = lr & 7;
    const size_t base  = (size_t)bh * 2048 * 64;   // qk/cqk [bh][2048][64]
    const size_t vbase = (size_t)bh * 64 * 2048;   // vt/cvt [bh][64][2048]
    // staging: linear LDS dest (lane*16B), swizzle folded into per-lane global src
    int lrow = l >> 3, lchk = l & 7;
    int lsw  = lchk ^ lrow;
    const u16* bsrc = Brows + base + (size_t)lrow * 64 + lsw * 8;                 // + (j0 + w*16 + it*8)*64
    const u16* vsrc = VTg + vbase + (size_t)(w*16 + lrow) * 2048 + lsw * 8;       // + it*8*2048 + j0
    u16* lbB = &Bt[0][(w*16) * 64];
    u16* lbV = &Vs[0][(w*16) * 64];
#define STAGE(bufp, j0v) do { \
    const u16* bp = bsrc + (size_t)((j0v) + w*16) * 64; \
    const u16* vp = vsrc + (j0v); \
    u16* lb = lbB + (bufp) * (64*64); \
    u16* lv = lbV + (bufp) * (64*64); \
    GLDS16(bp,            lb); \
    GLDS16(bp + 8*64,     lb + 8*64); \
    GLDS16(vp,            lv); \
    GLDS16(vp + 8*2048,   lv + 8*64); \
  } while (0)
    s16x8 aq[2][2];
    for (int qb = 0; qb < 2; ++qb)
        for (int ks = 0; ks < 2; ++ks)
            aq[qb][ks] = *(const s16x8*)(Arows + base + (size_t)(i0 + w*32 + qb*16 + lr) * 64 + ks*32 + lg*8);
    f32x4 acc[2][4] = {};
    float den[2] = {0.f, 0.f};
    const float SC2 = 0.125f * 1.44269504088896f;
    u16* pw = &Pt[w][0];
    STAGE(0, 0);
    for (int j0 = 0; j0 < 2048; j0 += 64) {
        int cur = (j0 >> 6) & 1;
        asm volatile("s_waitcnt vmcnt(0)" ::: "memory");
        __syncthreads();                          // staged cur visible; prev reads of cur^1 done
        if (j0 < 2048 - 64) STAGE(cur ^ 1, j0 + 64);
        // QK^T (swapped): s[qb][nf][q] = S[i = w*32+qb*16+lr][j = nf*16+lg*4+q]
        f32x4 s[2][4];
#pragma unroll
        for (int nf = 0; nf < 4; ++nf) {
            s[0][nf] = (f32x4){0.f,0.f,0.f,0.f};
            s[1][nf] = (f32x4){0.f,0.f,0.f,0.f};
#pragma unroll
            for (int ks = 0; ks < 2; ++ks) {
                const s16x8 af = *(const s16x8*)&Bt[cur][(nf*16 + lr)*64 + (((ks*4 + lg) ^ m7) * 8)];
                s[0][nf] = __builtin_amdgcn_mfma_f32_16x16x32_bf16(af, aq[0][ks], s[0][nf], 0, 0, 0);
                s[1][nf] = __builtin_amdgcn_mfma_f32_16x16x32_bf16(af, aq[1][ks], s[1][nf], 0, 0, 0);
            }
        }
        // softmax numerators -> bf16 -> wave-private P (no barrier: same-wave DS ordering)
#pragma unroll
        for (int qb = 0; qb < 2; ++qb)
#pragma unroll
            for (int nf = 0; nf < 4; ++nf) {
                float e0 = exp2f(s[qb][nf][0] * SC2), e1 = exp2f(s[qb][nf][1] * SC2);
                float e2 = exp2f(s[qb][nf][2] * SC2), e3 = exp2f(s[qb][nf][3] * SC2);
                den[qb] += (e0 + e1) + (e2 + e3);
                unsigned p0, p1;
                asm("v_cvt_pk_bf16_f32 %0, %1, %2" : "=v"(p0) : "v"(e0), "v"(e1));
                asm("v_cvt_pk_bf16_f32 %0, %1, %2" : "=v"(p1) : "v"(e2), "v"(e3));
                uint2 pp = { p0, p1 };
                *(uint2*)&pw[(qb*16 + lr)*64 + (((nf*2 + (lg >> 1)) ^ m7) * 8) + (lg & 1) * 4] = pp;
            }
        // PV: acc[qb][nf] += P[i][j] * V^T[d][j]
#pragma unroll
        for (int ks2 = 0; ks2 < 2; ++ks2) {
            const s16x8 ap0 = *(const s16x8*)&pw[lr*64        + (((ks2*4 + lg) ^ m7) * 8)];
            const s16x8 ap1 = *(const s16x8*)&pw[(16 + lr)*64 + (((ks2*4 + lg) ^ m7) * 8)];
#pragma unroll
            for (int nf = 0; nf < 4; ++nf) {
                const s16x8 bv = *(const s16x8*)&Vs[cur][(nf*16 + lr)*64 + (((ks2*4 + lg) ^ m7) * 8)];
                acc[0][nf] = __builtin_amdgcn_mfma_f32_16x16x32_bf16(ap0, bv, acc[0][nf], 0, 0, 0);
                acc[1][nf] = __builtin_amdgcn_mfma_f32_16x16x32_bf16(ap1, bv, acc[1][nf], 0, 0, 0);
            }
        }
    }
#pragma unroll
    for (int qb = 0; qb < 2; ++qb) {
        den[qb] += __shfl_xor(den[qb], 16);
        den[qb] += __shfl_xor(den[qb], 32);
    }
#pragma unroll
    for (int qb = 0; qb < 2; ++qb) {
        float rq[4];
#pragma unroll
        for (int q = 0; q < 4; ++q) rq[q] = 1.0f / __shfl(den[qb], lg*4 + q);
#pragma unroll
        for (int nf = 0; nf < 4; ++nf)
#pragma unroll
            for (int q = 0; q < 4; ++q) {
                int row = i0 + w*32 + qb*16 + lg*4 + q;
                int c = h*64 + nf*16 + lr;
                Out[((size_t)b*2048 + row)*512 + c] = f2bf(acc[qb][nf][q] * rq[q]);
            }
    }
#undef STAGE
}

// ---------------- output GEMM: merged bf16 [4096x512] @ W + bias -> d_out FLOAT32 ----------------
__global__ __launch_bounds__(256) void out_gemm(
    const u16* heads_base, const u16* wt, const float* bias0, const float* bias1, float* out) {
    __shared__ u16 Al[128][72];
    __shared__ u16 Bl[64][72];
    int z = blockIdx.z;
    const u16* A = heads_base + (size_t)z * 2097152;
    const u16* Wt = wt + (size_t)(4 + z) * 262144;
    const float* bias = z ? bias1 : bias0;
    float* dst = out + (size_t)z * 2097152;
    int m0 = blockIdx.y * 128, n0 = blockIdx.x * 64;
    int t = threadIdx.x, w = t >> 6, l = t & 63, lg = l >> 4, lr = l & 15;
    f32x4 acc[2][4] = {};
    for (int k0 = 0; k0 < 512; k0 += 64) {
        __syncthreads();
        for (int it = 0; it < 4; ++it) {
            int idx = it * 256 + t;
            int r = idx >> 3, c8 = (idx & 7) << 3;
            *(s16x8*)&Al[r][c8] = *(const s16x8*)(A + (size_t)(m0 + r) * 512 + k0 + c8);
        }
        for (int it = 0; it < 2; ++it) {
            int idx = it * 256 + t;
            int r = idx >> 3, c8 = (idx & 7) << 3;
            *(s16x8*)&Bl[r][c8] = *(const s16x8*)(Wt + (size_t)(n0 + r) * 512 + k0 + c8);
        }
        __syncthreads();
        for (int ks = 0; ks < 2; ++ks) {
            s16x8 a[2], b[4];
            for (int mi = 0; mi < 2; ++mi) a[mi] = *(const s16x8*)&Al[w*32 + mi*16 + lr][ks*32 + lg*8];
            for (int nf = 0; nf < 4; ++nf) b[nf] = *(const s16x8*)&Bl[nf*16 + lr][ks*32 + lg*8];
            for (int mi = 0; mi < 2; ++mi)
                for (int nf = 0; nf < 4; ++nf)
                    acc[mi][nf] = __builtin_amdgcn_mfma_f32_16x16x32_bf16(a[mi], b[nf], acc[mi][nf], 0, 0, 0);
        }
    }
    for (int mi = 0; mi < 2; ++mi) {
        int row = m0 + w*32 + mi*16 + lg*4;
        for (int nf = 0; nf < 4; ++nf) {
            int c = n0 + nf*16 + lr;
            float bv = bias[c];
            for (int r = 0; r < 4; ++r)
                dst[(size_t)(row + r) * 512 + c] = acc[mi][nf][r] + bv;
        }
    }
}

extern "C" void kernel_launch(void* const* d_in, const int* in_sizes, int n_in,
                              void* d_out, int out_size, void* d_ws, size_t ws_size,
                              hipStream_t stream) {
    const float* x      = (const float*)d_in[0];
    const float* ctx    = (const float*)d_in[1];
    const float* w_qk   = (const float*)d_in[2];
    const float* w_cqk  = (const float*)d_in[3];
    const float* w_v    = (const float*)d_in[4];
    const float* w_cv   = (const float*)d_in[5];
    const float* w_out  = (const float*)d_in[6];
    const float* b_out  = (const float*)d_in[7];
    const float* w_cout = (const float*)d_in[8];
    const float* b_cout = (const float*)d_in[9];

    u16* ws   = (u16*)d_ws;
    u16* wt   = ws;                       // 6 * 262144 bf16 weights^T
    u16* proj = ws + 1572864;
    u16* qk   = proj;
    u16* cqk  = proj + 2097152;
    u16* vt   = proj + 2 * 2097152;
    u16* cvt  = proj + 3 * 2097152;
    u16* outh = proj + 4 * 2097152;
    u16* ctxh = proj + 5 * 2097152;
    float* out = (float*)d_out;

    hipLaunchKernelGGL(transpose_w, dim3(8, 8, 6), dim3(256), 0, stream,
                       w_qk, w_cqk, w_v, w_cv, w_out, w_cout, wt);
    hipLaunchKernelGGL(proj_kernel, dim3(8, 32, 4), dim3(256), 0, stream, x, ctx, wt, proj);
    hipLaunchKernelGGL(attn_kernel, dim3(16, 16, 2), dim3(256), 0, stream, qk, cqk, vt, cvt, outh, ctxh);
    hipLaunchKernelGGL(out_gemm, dim3(8, 32, 2), dim3(256), 0, stream, outh, wt, b_out, b_cout, out);
}

// Round 8
// 120.429 us; speedup vs baseline: 1.8962x; 1.0463x over previous
//
#include <hip/hip_runtime.h>
#include <hip/hip_bf16.h>

typedef float f32x4 __attribute__((ext_vector_type(4)));
typedef short s16x8 __attribute__((ext_vector_type(8)));
typedef unsigned u32x4 __attribute__((ext_vector_type(4)));
typedef unsigned short u16;

__device__ __forceinline__ u16 f2bf(float f) {
    unsigned u = __float_as_uint(f);
    u += 0x7fffu + ((u >> 16) & 1u);   // RNE
    return (u16)(u >> 16);
}

#define GLDS16(gp, lp) __builtin_amdgcn_global_load_lds( \
    (const __attribute__((address_space(1))) void*)(gp), \
    (__attribute__((address_space(3))) void*)(lp), 16, 0, 0)

// ---------------- weight transpose + bf16 cast: wt[c][k] = w[k][c] ----------------
__global__ __launch_bounds__(256) void transpose_w(
    const float* w0, const float* w1, const float* w2,
    const float* w3, const float* w4, const float* w5, u16* wt_base) {
    __shared__ float tile[64][65];
    int z = blockIdx.z;
    const float* src = z==0?w0 : z==1?w1 : z==2?w2 : z==3?w3 : z==4?w4 : w5;
    u16* dst = wt_base + (size_t)z * 262144;
    int r0 = blockIdx.y * 64, c0 = blockIdx.x * 64;
    int t = threadIdx.x;
    for (int it = 0; it < 4; ++it) {
        int idx = it * 256 + t;
        int r = idx >> 4, c4 = (idx & 15) << 2;
        float4 v = *(const float4*)(src + (size_t)(r0 + r) * 512 + c0 + c4);
        tile[r][c4+0] = v.x; tile[r][c4+1] = v.y; tile[r][c4+2] = v.z; tile[r][c4+3] = v.w;
    }
    __syncthreads();
    for (int it = 0; it < 4; ++it) {
        int idx = it * 256 + t;
        int c = idx >> 4, r4 = (idx & 15) << 2;
        ushort4 o;
        o.x = f2bf(tile[r4+0][c]); o.y = f2bf(tile[r4+1][c]);
        o.z = f2bf(tile[r4+2][c]); o.w = f2bf(tile[r4+3][c]);
        *(ushort4*)(dst + (size_t)(c0 + c) * 512 + r0 + r4) = o;
    }
}

// ---------------- projections: [4096x512 f32] @ W -> bf16 ----------------
// z=0: x*w_qk -> qk [b,h,n,64] (PRE-SCALED by 0.125*log2e); z=1: x*w_v -> vt TR
// z=2: ctx*w_cqk -> cqk;        z=3: ctx*w_cv -> cvt TR
__global__ __launch_bounds__(256) void proj_kernel(
    const float* x, const float* ctx, const u16* wt, u16* proj_base) {
    __shared__ u16 Al[128][72];
    __shared__ u16 Bl[64][72];
    int z = blockIdx.z;
    const float* A = (z < 2) ? x : ctx;
    int p = (z==1) ? 2 : (z==2) ? 1 : z;
    const u16* Wt = wt + (size_t)p * 262144;
    u16* dst = proj_base + (size_t)p * 2097152;
    const float osc = (z == 0) ? 0.18033688011112042f : 1.0f;  // fold S-scale into qk
    int m0 = blockIdx.y * 128, n0 = blockIdx.x * 64;
    int t = threadIdx.x, w = t >> 6, l = t & 63, lg = l >> 4, lr = l & 15;
    f32x4 acc[2][4] = {};
    for (int k0 = 0; k0 < 512; k0 += 64) {
        __syncthreads();
        for (int it = 0; it < 8; ++it) {
            int idx = it * 256 + t;
            int r = idx >> 4, c4 = (idx & 15) << 2;
            float4 v = *(const float4*)(A + (size_t)(m0 + r) * 512 + k0 + c4);
            ushort4 o = { f2bf(v.x), f2bf(v.y), f2bf(v.z), f2bf(v.w) };
            *(ushort4*)&Al[r][c4] = o;
        }
        for (int it = 0; it < 2; ++it) {
            int idx = it * 256 + t;
            int r = idx >> 3, c8 = (idx & 7) << 3;
            *(s16x8*)&Bl[r][c8] = *(const s16x8*)(Wt + (size_t)(n0 + r) * 512 + k0 + c8);
        }
        __syncthreads();
        for (int ks = 0; ks < 2; ++ks) {
            s16x8 a[2], b[4];
            for (int mi = 0; mi < 2; ++mi) a[mi] = *(const s16x8*)&Al[w*32 + mi*16 + lr][ks*32 + lg*8];
            for (int nf = 0; nf < 4; ++nf) b[nf] = *(const s16x8*)&Bl[nf*16 + lr][ks*32 + lg*8];
            for (int mi = 0; mi < 2; ++mi)
                for (int nf = 0; nf < 4; ++nf)
                    acc[mi][nf] = __builtin_amdgcn_mfma_f32_16x16x32_bf16(a[mi], b[nf], acc[mi][nf], 0, 0, 0);
        }
    }
    if (z & 1) {
        for (int mi = 0; mi < 2; ++mi) {
            int row = m0 + w*32 + mi*16 + lg*4;
            int b = row >> 11, n = row & 2047;
            for (int nf = 0; nf < 4; ++nf) {
                int c = n0 + nf*16 + lr;
                int h = c >> 6, d = c & 63;
                ushort4 o = { f2bf(acc[mi][nf][0]), f2bf(acc[mi][nf][1]),
                              f2bf(acc[mi][nf][2]), f2bf(acc[mi][nf][3]) };
                *(ushort4*)(dst + (((size_t)b*8 + h)*64 + d)*2048 + n) = o;
            }
        }
    } else {
        for (int mi = 0; mi < 2; ++mi) {
            int row = m0 + w*32 + mi*16 + lg*4;
            for (int nf = 0; nf < 4; ++nf) {
                int c = n0 + nf*16 + lr;
                int h = c >> 6, d = c & 63;
                for (int r = 0; r < 4; ++r) {
                    int rr = row + r;
                    int b = rr >> 11, n = rr & 2047;
                    dst[(((size_t)b*8 + h)*2048 + n)*64 + d] = f2bf(acc[mi][nf][r] * osc);
                }
            }
        }
    }
}

// ---------------- fused bidirectional attention ----------------
// Swapped-QK in-register softmax; P kept fully in registers via
// permlane32_swap + permlane16_swap (validated in R7's first-pass check).
// Sync skeleton = R6's replay-proven: 2-buffer ring, vmcnt(0)+__syncthreads per tile.
__global__ __launch_bounds__(256, 2) void attn_kernel(
    const u16* qk, const u16* cqk, const u16* vtg, const u16* cvtg,
    u16* outh, u16* ctxh) {
    __shared__ u16 Bt[2][64 * 64];   // K-rows tiles [j][k], XOR-swizzled cols
    __shared__ u16 Vs[2][64 * 64];   // V^T tiles [d][j], XOR-swizzled cols
    int id = blockIdx.x + 16 * (blockIdx.y + 16 * blockIdx.z);
    int sv = ((id & 7) << 6) | (id >> 3);
    int dir = sv >> 8;
    int bh  = (sv >> 4) & 15;
    int i0  = (sv & 15) * 128;
    const u16* Arows = dir ? cqk : qk;
    const u16* Brows = dir ? qk  : cqk;
    const u16* VTg   = dir ? vtg : cvtg;
    u16* Out         = dir ? ctxh : outh;
    int b = bh >> 3, h = bh & 7;
    int t = threadIdx.x, w = t >> 6, l = t & 63, lg = l >> 4, lr = l & 15, m7 = lr & 7;
    const size_t base  = (size_t)bh * 2048 * 64;
    const size_t vbase = (size_t)bh * 64 * 2048;
    // staging: linear LDS dest, swizzle folded into per-lane global src
    int lrow = l >> 3, lchk = l & 7, lsw = lchk ^ lrow;
    const u16* bsrc = Brows + base + (size_t)lrow * 64 + lsw * 8;
    const u16* vsrc = VTg + vbase + (size_t)(w*16 + lrow) * 2048 + lsw * 8;
#define STAGE(BUF, J0V) do { \
    const u16* bp_ = bsrc + (size_t)((J0V) + w*16) * 64; \
    const u16* vp_ = vsrc + (J0V); \
    u16* lb_ = &Bt[BUF][(w*16) * 64]; \
    u16* lv_ = &Vs[BUF][(w*16) * 64]; \
    GLDS16(bp_,          lb_); \
    GLDS16(bp_ + 8*64,   lb_ + 8*64); \
    GLDS16(vp_,          lv_); \
    GLDS16(vp_ + 8*2048, lv_ + 8*64); \
  } while (0)
    // hoisted per-lane LDS read offsets (elements), shared by QK-A and PV-B reads
    int offK[2][4];
#pragma unroll
    for (int ks = 0; ks < 2; ++ks)
#pragma unroll
        for (int nf = 0; nf < 4; ++nf)
            offK[ks][nf] = (nf*16 + lr)*64 + (((ks*4 + lg) ^ m7) * 8);
    s16x8 aq[2][2];
#pragma unroll
    for (int qb = 0; qb < 2; ++qb)
#pragma unroll
        for (int ks = 0; ks < 2; ++ks)
            aq[qb][ks] = *(const s16x8*)(Arows + base + (size_t)(i0 + w*32 + qb*16 + lr) * 64 + ks*32 + lg*8);
    f32x4 acc[2][4] = {};
    float den[2] = {0.f, 0.f};
    STAGE(0, 0);
    for (int j0 = 0; j0 < 2048; j0 += 64) {
        int cur = (j0 >> 6) & 1;
        asm volatile("s_waitcnt vmcnt(0)" ::: "memory");
        __syncthreads();                          // staged cur visible; prev reads of cur^1 done
        if (j0 < 2048 - 64) STAGE(cur ^ 1, j0 + 64);
        const u16* bt_ = &Bt[cur][0];
        const u16* vs_ = &Vs[cur][0];
        // QK^T (swapped): s[qb][nf][q] = S[i=w*32+qb*16+lr][j=nf*16+lg*4+q] (pre-scaled)
        f32x4 s[2][4];
#pragma unroll
        for (int nf = 0; nf < 4; ++nf) {
            s[0][nf] = (f32x4){0.f,0.f,0.f,0.f};
            s[1][nf] = (f32x4){0.f,0.f,0.f,0.f};
#pragma unroll
            for (int ks = 0; ks < 2; ++ks) {
                const s16x8 af = *(const s16x8*)&bt_[offK[ks][nf]];
                s[0][nf] = __builtin_amdgcn_mfma_f32_16x16x32_bf16(af, aq[0][ks], s[0][nf], 0, 0, 0);
                s[1][nf] = __builtin_amdgcn_mfma_f32_16x16x32_bf16(af, aq[1][ks], s[1][nf], 0, 0, 0);
            }
        }
        // softmax numerators -> bf16 pairs -> PV A-frags fully in registers
#pragma unroll
        for (int qb = 0; qb < 2; ++qb) {
            unsigned PK0[4], PK1[4];
#pragma unroll
            for (int nf = 0; nf < 4; ++nf) {
                float e0 = exp2f(s[qb][nf][0]), e1 = exp2f(s[qb][nf][1]);
                float e2 = exp2f(s[qb][nf][2]), e3 = exp2f(s[qb][nf][3]);
                den[qb] += (e0 + e1) + (e2 + e3);
                asm("v_cvt_pk_bf16_f32 %0, %1, %2" : "=v"(PK0[nf]) : "v"(e0), "v"(e1));
                asm("v_cvt_pk_bf16_f32 %0, %1, %2" : "=v"(PK1[nf]) : "v"(e2), "v"(e3));
            }
#pragma unroll
            for (int ks2 = 0; ks2 < 2; ++ks2) {
                unsigned a0 = PK0[2*ks2], b0 = PK0[2*ks2+1];
                unsigned a1 = PK1[2*ks2], b1 = PK1[2*ks2+1];
                asm("v_permlane32_swap_b32 %0, %1" : "+v"(a0), "+v"(b0));
                asm("v_permlane16_swap_b32 %0, %1" : "+v"(a0), "+v"(b0));
                asm("v_permlane32_swap_b32 %0, %1" : "+v"(a1), "+v"(b1));
                asm("v_permlane16_swap_b32 %0, %1" : "+v"(a1), "+v"(b1));
                u32x4 fw = { a0, a1, b0, b1 };
                s16x8 ap = __builtin_bit_cast(s16x8, fw);
#pragma unroll
                for (int nf = 0; nf < 4; ++nf) {
                    const s16x8 bv = *(const s16x8*)&vs_[offK[ks2][nf]];
                    acc[qb][nf] = __builtin_amdgcn_mfma_f32_16x16x32_bf16(ap, bv, acc[qb][nf], 0, 0, 0);
                }
            }
        }
    }
#pragma unroll
    for (int qb = 0; qb < 2; ++qb) {
        den[qb] += __shfl_xor(den[qb], 16);
        den[qb] += __shfl_xor(den[qb], 32);
    }
#pragma unroll
    for (int qb = 0; qb < 2; ++qb) {
        float rq[4];
#pragma unroll
        for (int q = 0; q < 4; ++q) rq[q] = 1.0f / __shfl(den[qb], lg*4 + q);
#pragma unroll
        for (int nf = 0; nf < 4; ++nf)
#pragma unroll
            for (int q = 0; q < 4; ++q) {
                int row = i0 + w*32 + qb*16 + lg*4 + q;
                int c = h*64 + nf*16 + lr;
                Out[((size_t)b*2048 + row)*512 + c] = f2bf(acc[qb][nf][q] * rq[q]);
            }
    }
#undef STAGE
}

// ---------------- output GEMM: merged bf16 [4096x512] @ W + bias -> d_out FLOAT32 ----------------
__global__ __launch_bounds__(256) void out_gemm(
    const u16* heads_base, const u16* wt, const float* bias0, const float* bias1, float* out) {
    __shared__ u16 Al[128][72];
    __shared__ u16 Bl[64][72];
    int z = blockIdx.z;
    const u16* A = heads_base + (size_t)z * 2097152;
    const u16* Wt = wt + (size_t)(4 + z) * 262144;
    const float* bias = z ? bias1 : bias0;
    float* dst = out + (size_t)z * 2097152;
    int m0 = blockIdx.y * 128, n0 = blockIdx.x * 64;
    int t = threadIdx.x, w = t >> 6, l = t & 63, lg = l >> 4, lr = l & 15;
    f32x4 acc[2][4] = {};
    for (int k0 = 0; k0 < 512; k0 += 64) {
        __syncthreads();
        for (int it = 0; it < 4; ++it) {
            int idx = it * 256 + t;
            int r = idx >> 3, c8 = (idx & 7) << 3;
            *(s16x8*)&Al[r][c8] = *(const s16x8*)(A + (size_t)(m0 + r) * 512 + k0 + c8);
        }
        for (int it = 0; it < 2; ++it) {
            int idx = it * 256 + t;
            int r = idx >> 3, c8 = (idx & 7) << 3;
            *(s16x8*)&Bl[r][c8] = *(const s16x8*)(Wt + (size_t)(n0 + r) * 512 + k0 + c8);
        }
        __syncthreads();
        for (int ks = 0; ks < 2; ++ks) {
            s16x8 a[2], b[4];
            for (int mi = 0; mi < 2; ++mi) a[mi] = *(const s16x8*)&Al[w*32 + mi*16 + lr][ks*32 + lg*8];
            for (int nf = 0; nf < 4; ++nf) b[nf] = *(const s16x8*)&Bl[nf*16 + lr][ks*32 + lg*8];
            for (int mi = 0; mi < 2; ++mi)
                for (int nf = 0; nf < 4; ++nf)
                    acc[mi][nf] = __builtin_amdgcn_mfma_f32_16x16x32_bf16(a[mi], b[nf], acc[mi][nf], 0, 0, 0);
        }
    }
    for (int mi = 0; mi < 2; ++mi) {
        int row = m0 + w*32 + mi*16 + lg*4;
        for (int nf = 0; nf < 4; ++nf) {
            int c = n0 + nf*16 + lr;
            float bv = bias[c];
            for (int r = 0; r < 4; ++r)
                dst[(size_t)(row + r) * 512 + c] = acc[mi][nf][r] + bv;
        }
    }
}

extern "C" void kernel_launch(void* const* d_in, const int* in_sizes, int n_in,
                              void* d_out, int out_size, void* d_ws, size_t ws_size,
                              hipStream_t stream) {
    const float* x      = (const float*)d_in[0];
    const float* ctx    = (const float*)d_in[1];
    const float* w_qk   = (const float*)d_in[2];
    const float* w_cqk  = (const float*)d_in[3];
    const float* w_v    = (const float*)d_in[4];
    const float* w_cv   = (const float*)d_in[5];
    const float* w_out  = (const float*)d_in[6];
    const float* b_out  = (const float*)d_in[7];
    const float* w_cout = (const float*)d_in[8];
    const float* b_cout = (const float*)d_in[9];

    u16* ws   = (u16*)d_ws;
    u16* wt   = ws;                       // 6 * 262144 bf16 weights^T
    u16* proj = ws + 1572864;
    u16* qk   = proj;                     // pre-scaled by 0.125*log2(e)
    u16* cqk  = proj + 2097152;
    u16* vt   = proj + 2 * 2097152;
    u16* cvt  = proj + 3 * 2097152;
    u16* outh = proj + 4 * 2097152;
    u16* ctxh = proj + 5 * 2097152;
    float* out = (float*)d_out;

    hipLaunchKernelGGL(transpose_w, dim3(8, 8, 6), dim3(256), 0, stream,
                       w_qk, w_cqk, w_v, w_cv, w_out, w_cout, wt);
    hipLaunchKernelGGL(proj_kernel, dim3(8, 32, 4), dim3(256), 0, stream, x, ctx, wt, proj);
    hipLaunchKernelGGL(attn_kernel, dim3(16, 16, 2), dim3(256), 0, stream, qk, cqk, vt, cvt, outh, ctxh);
    hipLaunchKernelGGL(out_gemm, dim3(8, 32, 2), dim3(256), 0, stream, outh, wt, b_out, b_cout, out);
}

// Round 10
// 100.580 us; speedup vs baseline: 2.2705x; 1.1973x over previous
//
#include <hip/hip_runtime.h>
#include <hip/hip_bf16.h>

typedef float f32x4 __attribute__((ext_vector_type(4)));
typedef short s16x8 __attribute__((ext_vector_type(8)));
typedef unsigned u32x4 __attribute__((ext_vector_type(4)));
typedef unsigned short u16;

__device__ __forceinline__ u16 f2bf(float f) {
    unsigned u = __float_as_uint(f);
    u += 0x7fffu + ((u >> 16) & 1u);   // RNE
    return (u16)(u >> 16);
}

// 2^x for bounded inputs. MUST be compiler-visible (no raw inline asm):
// an opaque asm v_exp_f32 reading an MFMA destination bypasses the backend's
// MFMA-write->VALU-read hazard handling (R9 failure: absmax 7.1e-3).
__device__ __forceinline__ float fast_exp2(float x) {
#if __has_builtin(__builtin_amdgcn_exp2f)
    return __builtin_amdgcn_exp2f(x);
#else
    return exp2f(x);
#endif
}

#define GLDS16(gp, lp) __builtin_amdgcn_global_load_lds( \
    (const __attribute__((address_space(1))) void*)(gp), \
    (__attribute__((address_space(3))) void*)(lp), 16, 0, 0)

// ---------------- weight transpose + bf16 cast: wt[c][k] = w[k][c] ----------------
__global__ __launch_bounds__(256) void transpose_w(
    const float* w0, const float* w1, const float* w2,
    const float* w3, const float* w4, const float* w5, u16* wt_base) {
    __shared__ float tile[64][65];
    int z = blockIdx.z;
    const float* src = z==0?w0 : z==1?w1 : z==2?w2 : z==3?w3 : z==4?w4 : w5;
    u16* dst = wt_base + (size_t)z * 262144;
    int r0 = blockIdx.y * 64, c0 = blockIdx.x * 64;
    int t = threadIdx.x;
    for (int it = 0; it < 4; ++it) {
        int idx = it * 256 + t;
        int r = idx >> 4, c4 = (idx & 15) << 2;
        float4 v = *(const float4*)(src + (size_t)(r0 + r) * 512 + c0 + c4);
        tile[r][c4+0] = v.x; tile[r][c4+1] = v.y; tile[r][c4+2] = v.z; tile[r][c4+3] = v.w;
    }
    __syncthreads();
    for (int it = 0; it < 4; ++it) {
        int idx = it * 256 + t;
        int c = idx >> 4, r4 = (idx & 15) << 2;
        ushort4 o;
        o.x = f2bf(tile[r4+0][c]); o.y = f2bf(tile[r4+1][c]);
        o.z = f2bf(tile[r4+2][c]); o.w = f2bf(tile[r4+3][c]);
        *(ushort4*)(dst + (size_t)(c0 + c) * 512 + r0 + r4) = o;
    }
}

// ---------------- projections: [4096x512 f32] @ W -> bf16 ----------------
// z=0: x*w_qk -> qk [b,h,n,64] (PRE-SCALED by 0.125*log2e); z=1: x*w_v -> vt TR
// z=2: ctx*w_cqk -> cqk;        z=3: ctx*w_cv -> cvt TR
__global__ __launch_bounds__(256) void proj_kernel(
    const float* x, const float* ctx, const u16* wt, u16* proj_base) {
    __shared__ u16 Al[128][72];
    __shared__ u16 Bl[64][72];
    int z = blockIdx.z;
    const float* A = (z < 2) ? x : ctx;
    int p = (z==1) ? 2 : (z==2) ? 1 : z;
    const u16* Wt = wt + (size_t)p * 262144;
    u16* dst = proj_base + (size_t)p * 2097152;
    const float osc = (z == 0) ? 0.18033688011112042f : 1.0f;  // fold S-scale into qk
    int m0 = blockIdx.y * 128, n0 = blockIdx.x * 64;
    int t = threadIdx.x, w = t >> 6, l = t & 63, lg = l >> 4, lr = l & 15;
    f32x4 acc[2][4] = {};
    for (int k0 = 0; k0 < 512; k0 += 64) {
        __syncthreads();
        for (int it = 0; it < 8; ++it) {
            int idx = it * 256 + t;
            int r = idx >> 4, c4 = (idx & 15) << 2;
            float4 v = *(const float4*)(A + (size_t)(m0 + r) * 512 + k0 + c4);
            ushort4 o = { f2bf(v.x), f2bf(v.y), f2bf(v.z), f2bf(v.w) };
            *(ushort4*)&Al[r][c4] = o;
        }
        for (int it = 0; it < 2; ++it) {
            int idx = it * 256 + t;
            int r = idx >> 3, c8 = (idx & 7) << 3;
            *(s16x8*)&Bl[r][c8] = *(const s16x8*)(Wt + (size_t)(n0 + r) * 512 + k0 + c8);
        }
        __syncthreads();
        for (int ks = 0; ks < 2; ++ks) {
            s16x8 a[2], b[4];
            for (int mi = 0; mi < 2; ++mi) a[mi] = *(const s16x8*)&Al[w*32 + mi*16 + lr][ks*32 + lg*8];
            for (int nf = 0; nf < 4; ++nf) b[nf] = *(const s16x8*)&Bl[nf*16 + lr][ks*32 + lg*8];
            for (int mi = 0; mi < 2; ++mi)
                for (int nf = 0; nf < 4; ++nf)
                    acc[mi][nf] = __builtin_amdgcn_mfma_f32_16x16x32_bf16(a[mi], b[nf], acc[mi][nf], 0, 0, 0);
        }
    }
    if (z & 1) {
        for (int mi = 0; mi < 2; ++mi) {
            int row = m0 + w*32 + mi*16 + lg*4;
            int b = row >> 11, n = row & 2047;
            for (int nf = 0; nf < 4; ++nf) {
                int c = n0 + nf*16 + lr;
                int h = c >> 6, d = c & 63;
                ushort4 o = { f2bf(acc[mi][nf][0]), f2bf(acc[mi][nf][1]),
                              f2bf(acc[mi][nf][2]), f2bf(acc[mi][nf][3]) };
                *(ushort4*)(dst + (((size_t)b*8 + h)*64 + d)*2048 + n) = o;
            }
        }
    } else {
        for (int mi = 0; mi < 2; ++mi) {
            int row = m0 + w*32 + mi*16 + lg*4;
            for (int nf = 0; nf < 4; ++nf) {
                int c = n0 + nf*16 + lr;
                int h = c >> 6, d = c & 63;
                for (int r = 0; r < 4; ++r) {
                    int rr = row + r;
                    int b = rr >> 11, n = rr & 2047;
                    dst[(((size_t)b*8 + h)*2048 + n)*64 + d] = f2bf(acc[mi][nf][r] * osc);
                }
            }
        }
    }
}

// ---------------- fused bidirectional attention ----------------
// Swapped-QK in-register softmax; P fully in registers via permlane swaps.
// Sync skeleton = replay-proven 2-buffer ring, vmcnt(0)+__syncthreads per tile.
// 4 blocks/CU resident for latency hiding.
__global__ __launch_bounds__(256, 4) void attn_kernel(
    const u16* qk, const u16* cqk, const u16* vtg, const u16* cvtg,
    u16* outh, u16* ctxh) {
    __shared__ u16 Bt[2][64 * 64];   // K-rows tiles [j][k], XOR-swizzled cols
    __shared__ u16 Vs[2][64 * 64];   // V^T tiles [d][j], XOR-swizzled cols
    int id = blockIdx.x + 16 * (blockIdx.y + 16 * blockIdx.z);
    int sv = ((id & 7) << 6) | (id >> 3);
    int dir = sv >> 8;
    int bh  = (sv >> 4) & 15;
    int i0  = (sv & 15) * 128;
    const u16* Arows = dir ? cqk : qk;
    const u16* Brows = dir ? qk  : cqk;
    const u16* VTg   = dir ? vtg : cvtg;
    u16* Out         = dir ? ctxh : outh;
    int b = bh >> 3, h = bh & 7;
    int t = threadIdx.x, w = t >> 6, l = t & 63, lg = l >> 4, lr = l & 15, m7 = lr & 7;
    const size_t base  = (size_t)bh * 2048 * 64;
    const size_t vbase = (size_t)bh * 64 * 2048;
    // staging: linear LDS dest, swizzle folded into per-lane global src
    int lrow = l >> 3, lchk = l & 7, lsw = lchk ^ lrow;
    const u16* bsrc = Brows + base + (size_t)lrow * 64 + lsw * 8;
    const u16* vsrc = VTg + vbase + (size_t)(w*16 + lrow) * 2048 + lsw * 8;
#define STAGE(BUF, J0V) do { \
    const u16* bp_ = bsrc + (size_t)((J0V) + w*16) * 64; \
    const u16* vp_ = vsrc + (J0V); \
    u16* lb_ = &Bt[BUF][(w*16) * 64]; \
    u16* lv_ = &Vs[BUF][(w*16) * 64]; \
    GLDS16(bp_,          lb_); \
    GLDS16(bp_ + 8*64,   lb_ + 8*64); \
    GLDS16(vp_,          lv_); \
    GLDS16(vp_ + 8*2048, lv_ + 8*64); \
  } while (0)
    // hoisted per-lane LDS read offsets (elements), shared by QK-A and PV-B reads
    int offK[2][4];
#pragma unroll
    for (int ks = 0; ks < 2; ++ks)
#pragma unroll
        for (int nf = 0; nf < 4; ++nf)
            offK[ks][nf] = (nf*16 + lr)*64 + (((ks*4 + lg) ^ m7) * 8);
    s16x8 aq[2][2];
#pragma unroll
    for (int qb = 0; qb < 2; ++qb)
#pragma unroll
        for (int ks = 0; ks < 2; ++ks)
            aq[qb][ks] = *(const s16x8*)(Arows + base + (size_t)(i0 + w*32 + qb*16 + lr) * 64 + ks*32 + lg*8);
    f32x4 acc[2][4] = {};
    float den[2] = {0.f, 0.f};
    STAGE(0, 0);
    for (int j0 = 0; j0 < 2048; j0 += 64) {
        int cur = (j0 >> 6) & 1;
        asm volatile("s_waitcnt vmcnt(0)" ::: "memory");
        __syncthreads();                          // staged cur visible; prev reads of cur^1 done
        if (j0 < 2048 - 64) STAGE(cur ^ 1, j0 + 64);
        const u16* bt_ = &Bt[cur][0];
        const u16* vs_ = &Vs[cur][0];
        // QK^T (swapped): s[qb][nf][q] = S[i=w*32+qb*16+lr][j=nf*16+lg*4+q] (pre-scaled)
        f32x4 s[2][4];
#pragma unroll
        for (int nf = 0; nf < 4; ++nf) {
            s[0][nf] = (f32x4){0.f,0.f,0.f,0.f};
            s[1][nf] = (f32x4){0.f,0.f,0.f,0.f};
#pragma unroll
            for (int ks = 0; ks < 2; ++ks) {
                const s16x8 af = *(const s16x8*)&bt_[offK[ks][nf]];
                s[0][nf] = __builtin_amdgcn_mfma_f32_16x16x32_bf16(af, aq[0][ks], s[0][nf], 0, 0, 0);
                s[1][nf] = __builtin_amdgcn_mfma_f32_16x16x32_bf16(af, aq[1][ks], s[1][nf], 0, 0, 0);
            }
        }
        // softmax numerators -> bf16 pairs -> PV A-frags fully in registers
#pragma unroll
        for (int qb = 0; qb < 2; ++qb) {
            unsigned PK0[4], PK1[4];
#pragma unroll
            for (int nf = 0; nf < 4; ++nf) {
                float e0 = fast_exp2(s[qb][nf][0]), e1 = fast_exp2(s[qb][nf][1]);
                float e2 = fast_exp2(s[qb][nf][2]), e3 = fast_exp2(s[qb][nf][3]);
                den[qb] += (e0 + e1) + (e2 + e3);
                asm("v_cvt_pk_bf16_f32 %0, %1, %2" : "=v"(PK0[nf]) : "v"(e0), "v"(e1));
                asm("v_cvt_pk_bf16_f32 %0, %1, %2" : "=v"(PK1[nf]) : "v"(e2), "v"(e3));
            }
#pragma unroll
            for (int ks2 = 0; ks2 < 2; ++ks2) {
                unsigned a0 = PK0[2*ks2], b0 = PK0[2*ks2+1];
                unsigned a1 = PK1[2*ks2], b1 = PK1[2*ks2+1];
                asm("v_permlane32_swap_b32 %0, %1" : "+v"(a0), "+v"(b0));
                asm("v_permlane16_swap_b32 %0, %1" : "+v"(a0), "+v"(b0));
                asm("v_permlane32_swap_b32 %0, %1" : "+v"(a1), "+v"(b1));
                asm("v_permlane16_swap_b32 %0, %1" : "+v"(a1), "+v"(b1));
                u32x4 fw = { a0, a1, b0, b1 };
                s16x8 ap = __builtin_bit_cast(s16x8, fw);
#pragma unroll
                for (int nf = 0; nf < 4; ++nf) {
                    const s16x8 bv = *(const s16x8*)&vs_[offK[ks2][nf]];
                    acc[qb][nf] = __builtin_amdgcn_mfma_f32_16x16x32_bf16(ap, bv, acc[qb][nf], 0, 0, 0);
                }
            }
        }
    }
#pragma unroll
    for (int qb = 0; qb < 2; ++qb) {
        den[qb] += __shfl_xor(den[qb], 16);
        den[qb] += __shfl_xor(den[qb], 32);
    }
#pragma unroll
    for (int qb = 0; qb < 2; ++qb) {
        float rq[4];
#pragma unroll
        for (int q = 0; q < 4; ++q) rq[q] = 1.0f / __shfl(den[qb], lg*4 + q);
#pragma unroll
        for (int nf = 0; nf < 4; ++nf)
#pragma unroll
            for (int q = 0; q < 4; ++q) {
                int row = i0 + w*32 + qb*16 + lg*4 + q;
                int c = h*64 + nf*16 + lr;
                Out[((size_t)b*2048 + row)*512 + c] = f2bf(acc[qb][nf][q] * rq[q]);
            }
    }
#undef STAGE
}

// ---------------- output GEMM: merged bf16 [4096x512] @ W + bias -> d_out FLOAT32 ----------------
__global__ __launch_bounds__(256) void out_gemm(
    const u16* heads_base, const u16* wt, const float* bias0, const float* bias1, float* out) {
    __shared__ u16 Al[128][72];
    __shared__ u16 Bl[64][72];
    int z = blockIdx.z;
    const u16* A = heads_base + (size_t)z * 2097152;
    const u16* Wt = wt + (size_t)(4 + z) * 262144;
    const float* bias = z ? bias1 : bias0;
    float* dst = out + (size_t)z * 2097152;
    int m0 = blockIdx.y * 128, n0 = blockIdx.x * 64;
    int t = threadIdx.x, w = t >> 6, l = t & 63, lg = l >> 4, lr = l & 15;
    f32x4 acc[2][4] = {};
    for (int k0 = 0; k0 < 512; k0 += 64) {
        __syncthreads();
        for (int it = 0; it < 4; ++it) {
            int idx = it * 256 + t;
            int r = idx >> 3, c8 = (idx & 7) << 3;
            *(s16x8*)&Al[r][c8] = *(const s16x8*)(A + (size_t)(m0 + r) * 512 + k0 + c8);
        }
        for (int it = 0; it < 2; ++it) {
            int idx = it * 256 + t;
            int r = idx >> 3, c8 = (idx & 7) << 3;
            *(s16x8*)&Bl[r][c8] = *(const s16x8*)(Wt + (size_t)(n0 + r) * 512 + k0 + c8);
        }
        __syncthreads();
        for (int ks = 0; ks < 2; ++ks) {
            s16x8 a[2], b[4];
            for (int mi = 0; mi < 2; ++mi) a[mi] = *(const s16x8*)&Al[w*32 + mi*16 + lr][ks*32 + lg*8];
            for (int nf = 0; nf < 4; ++nf) b[nf] = *(const s16x8*)&Bl[nf*16 + lr][ks*32 + lg*8];
            for (int mi = 0; mi < 2; ++mi)
                for (int nf = 0; nf < 4; ++nf)
                    acc[mi][nf] = __builtin_amdgcn_mfma_f32_16x16x32_bf16(a[mi], b[nf], acc[mi][nf], 0, 0, 0);
        }
    }
    for (int mi = 0; mi < 2; ++mi) {
        int row = m0 + w*32 + mi*16 + lg*4;
        for (int nf = 0; nf < 4; ++nf) {
            int c = n0 + nf*16 + lr;
            float bv = bias[c];
            for (int r = 0; r < 4; ++r)
                dst[(size_t)(row + r) * 512 + c] = acc[mi][nf][r] + bv;
        }
    }
}

extern "C" void kernel_launch(void* const* d_in, const int* in_sizes, int n_in,
                              void* d_out, int out_size, void* d_ws, size_t ws_size,
                              hipStream_t stream) {
    const float* x      = (const float*)d_in[0];
    const float* ctx    = (const float*)d_in[1];
    const float* w_qk   = (const float*)d_in[2];
    const float* w_cqk  = (const float*)d_in[3];
    const float* w_v    = (const float*)d_in[4];
    const float* w_cv   = (const float*)d_in[5];
    const float* w_out  = (const float*)d_in[6];
    const float* b_out  = (const float*)d_in[7];
    const float* w_cout = (const float*)d_in[8];
    const float* b_cout = (const float*)d_in[9];

    u16* ws   = (u16*)d_ws;
    u16* wt   = ws;                       // 6 * 262144 bf16 weights^T
    u16* proj = ws + 1572864;
    u16* qk   = proj;                     // pre-scaled by 0.125*log2(e)
    u16* cqk  = proj + 2097152;
    u16* vt   = proj + 2 * 2097152;
    u16* cvt  = proj + 3 * 2097152;
    u16* outh = proj + 4 * 2097152;
    u16* ctxh = proj + 5 * 2097152;
    float* out = (float*)d_out;

    hipLaunchKernelGGL(transpose_w, dim3(8, 8, 6), dim3(256), 0, stream,
                       w_qk, w_cqk, w_v, w_cv, w_out, w_cout, wt);
    hipLaunchKernelGGL(proj_kernel, dim3(8, 32, 4), dim3(256), 0, stream, x, ctx, wt, proj);
    hipLaunchKernelGGL(attn_kernel, dim3(16, 16, 2), dim3(256), 0, stream, qk, cqk, vt, cvt, outh, ctxh);
    hipLaunchKernelGGL(out_gemm, dim3(8, 32, 2), dim3(256), 0, stream, outh, wt, b_out, b_cout, out);
}